// Round 1
// baseline (263.255 us; speedup 1.0000x reference)
//
#include <hip/hip_runtime.h>
#include <math.h>

// NeighborList: P = N*(N-1)/2 candidate pairs, minimum-image distance,
// cutoff mask, fixed-shape outputs.
// out layout (float32, concatenated): [P] pair_i, [P] pair_j, [P*3] pair_diff, [P] pair_dist

#define NL_CUTOFF 5.0f

struct CellRows {
    float r0x, r0y, r0z;
    float r1x, r1y, r1z;
    float r2x, r2y, r2z;
};

__device__ __forceinline__ void pair_compute(
    const float* __restrict__ xyz, const CellRows& c,
    int ii, int jj,
    float& oi, float& oj, float& odx, float& ody, float& odz, float& orr)
{
    // raw displacement (IEEE, no contraction — must bit-match numpy f32)
    float dx = __fsub_rn(xyz[3 * ii + 0], xyz[3 * jj + 0]);
    float dy = __fsub_rn(xyz[3 * ii + 1], xyz[3 * jj + 1]);
    float dz = __fsub_rn(xyz[3 * ii + 2], xyz[3 * jj + 2]);

    // z -> y -> x minimum image (NNPOps convention), sequential updates
    float s = rintf(__fdiv_rn(dz, c.r2z));
    dx = __fsub_rn(dx, __fmul_rn(s, c.r2x));
    dy = __fsub_rn(dy, __fmul_rn(s, c.r2y));
    dz = __fsub_rn(dz, __fmul_rn(s, c.r2z));

    s = rintf(__fdiv_rn(dy, c.r1y));
    dx = __fsub_rn(dx, __fmul_rn(s, c.r1x));
    dy = __fsub_rn(dy, __fmul_rn(s, c.r1y));
    dz = __fsub_rn(dz, __fmul_rn(s, c.r1z));

    s = rintf(__fdiv_rn(dx, c.r0x));
    dx = __fsub_rn(dx, __fmul_rn(s, c.r0x));
    dy = __fsub_rn(dy, __fmul_rn(s, c.r0y));
    dz = __fsub_rn(dz, __fmul_rn(s, c.r0z));

    float ss = __fadd_rn(__fadd_rn(__fmul_rn(dx, dx), __fmul_rn(dy, dy)),
                         __fmul_rn(dz, dz));
    float r = __fsqrt_rn(ss);
    bool m = (r < NL_CUTOFF);

    oi  = m ? (float)ii : -1.0f;
    oj  = m ? (float)jj : -1.0f;
    odx = m ? dx : 0.0f;
    ody = m ? dy : 0.0f;
    odz = m ? dz : 0.0f;
    orr = m ? r  : 0.0f;
}

__global__ __launch_bounds__(256) void nl_kernel(
    const float* __restrict__ xyz,
    const float* __restrict__ cell,
    const int*   __restrict__ idx_i,
    const int*   __restrict__ idx_j,
    float* __restrict__ out,
    long long P)
{
    CellRows c;
    c.r0x = cell[0]; c.r0y = cell[1]; c.r0z = cell[2];
    c.r1x = cell[3]; c.r1y = cell[4]; c.r1z = cell[5];
    c.r2x = cell[6]; c.r2y = cell[7]; c.r2z = cell[8];

    float* __restrict__ out_i = out;
    float* __restrict__ out_j = out + P;
    float* __restrict__ out_d = out + 2 * P;   // [P,3] row-major
    float* __restrict__ out_r = out + 5 * P;

    const long long nquad  = P >> 2;
    const long long stride = (long long)gridDim.x * blockDim.x;
    const long long tid0   = (long long)blockIdx.x * blockDim.x + threadIdx.x;

    // main: 4 pairs per thread, fully vectorized loads/stores
    for (long long q = tid0; q < nquad; q += stride) {
        const int4 vi = ((const int4*)idx_i)[q];
        const int4 vj = ((const int4*)idx_j)[q];
        const int ia[4] = {vi.x, vi.y, vi.z, vi.w};
        const int ja[4] = {vj.x, vj.y, vj.z, vj.w};

        float oia[4], oja[4], ora[4], od[12];
#pragma unroll
        for (int k = 0; k < 4; ++k) {
            pair_compute(xyz, c, ia[k], ja[k],
                         oia[k], oja[k], od[3 * k + 0], od[3 * k + 1],
                         od[3 * k + 2], ora[k]);
        }

        ((float4*)out_i)[q] = make_float4(oia[0], oia[1], oia[2], oia[3]);
        ((float4*)out_j)[q] = make_float4(oja[0], oja[1], oja[2], oja[3]);
        ((float4*)out_r)[q] = make_float4(ora[0], ora[1], ora[2], ora[3]);
        float4* dd = (float4*)(out_d + 3 * (q << 2));
        dd[0] = make_float4(od[0], od[1],  od[2],  od[3]);
        dd[1] = make_float4(od[4], od[5],  od[6],  od[7]);
        dd[2] = make_float4(od[8], od[9],  od[10], od[11]);
    }

    // tail: P % 4 leftover pairs (P is divisible by 4 for N=8192, but be safe)
    for (long long p = (nquad << 2) + tid0; p < P; p += stride) {
        float oi, oj, dx, dy, dz, rr;
        pair_compute(xyz, c, idx_i[p], idx_j[p], oi, oj, dx, dy, dz, rr);
        out_i[p] = oi;
        out_j[p] = oj;
        out_d[3 * p + 0] = dx;
        out_d[3 * p + 1] = dy;
        out_d[3 * p + 2] = dz;
        out_r[p] = rr;
    }
}

extern "C" void kernel_launch(void* const* d_in, const int* in_sizes, int n_in,
                              void* d_out, int out_size, void* d_ws, size_t ws_size,
                              hipStream_t stream) {
    const float* xyz   = (const float*)d_in[0];
    const float* cell  = (const float*)d_in[1];
    const int*   idx_i = (const int*)d_in[2];
    const int*   idx_j = (const int*)d_in[3];
    float* out = (float*)d_out;

    const long long P = (long long)in_sizes[2];

    const int block = 256;
    long long nquad = P >> 2;
    long long blocks_needed = (nquad + block - 1) / block;
    int grid = (int)(blocks_needed < 2048 ? (blocks_needed > 0 ? blocks_needed : 1)
                                          : 2048);

    nl_kernel<<<grid, block, 0, stream>>>(xyz, cell, idx_i, idx_j, out, P);
}